// Round 3
// baseline (621.931 us; speedup 1.0000x reference)
//
#include <hip/hip_runtime.h>
#include <math.h>

#define BLOCK 256
// Each block owns 2*BLOCK consecutive points; thread t owns points t and t+BLOCK
// (both halves coalesced). 2 pts/thread halves LDS-weight reads per FMA.

__device__ __forceinline__ void geom_one(int idx, bool valid, int n,
                                         const float* __restrict__ positions,
                                         const float* __restrict__ scales,
                                         const float* __restrict__ rotations,
                                         const float* __restrict__ opacity,
                                         float* __restrict__ out)
{
    const size_t base = (size_t)(valid ? idx : (n - 1));   // clamped load addr

    const float px = positions[base * 3 + 0];
    const float py = positions[base * 3 + 1];
    const float pz = positions[base * 3 + 2];

    const float s0 = __expf(scales[base * 3 + 0]);
    const float s1 = __expf(scales[base * 3 + 1]);
    const float s2 = __expf(scales[base * 3 + 2]);

    float qw = rotations[base * 4 + 0];
    float qx = rotations[base * 4 + 1];
    float qy = rotations[base * 4 + 2];
    float qz = rotations[base * 4 + 3];
    const float inv = rsqrtf(qw * qw + qx * qx + qy * qy + qz * qz);
    qw *= inv; qx *= inv; qy *= inv; qz *= inv;

    float op = opacity[base];
    op = 1.0f / (1.0f + __expf(-op));

    const float r00 = 1.0f - 2.0f * (qy * qy + qz * qz);
    const float r01 = 2.0f * (qx * qy - qw * qz);
    const float r02 = 2.0f * (qx * qz + qw * qy);
    const float r10 = 2.0f * (qx * qy + qw * qz);
    const float r11 = 1.0f - 2.0f * (qx * qx + qz * qz);
    const float r12 = 2.0f * (qy * qz - qw * qx);
    const float r20 = 2.0f * (qx * qz - qw * qy);
    const float r21 = 2.0f * (qy * qz + qw * qx);
    const float r22 = 1.0f - 2.0f * (qx * qx + qy * qy);

    const float v0 = s0 * s0, v1 = s1 * s1, v2 = s2 * s2;
    const float c00 = r00 * r00 * v0 + r01 * r01 * v1 + r02 * r02 * v2;
    const float c01 = r00 * r10 * v0 + r01 * r11 * v1 + r02 * r12 * v2;
    const float c02 = r00 * r20 * v0 + r01 * r21 * v1 + r02 * r22 * v2;
    const float c11 = r10 * r10 * v0 + r11 * r11 * v1 + r12 * r12 * v2;
    const float c12 = r10 * r20 * v0 + r11 * r21 * v1 + r12 * r22 * v2;
    const float c22 = r20 * r20 * v0 + r21 * r21 * v1 + r22 * r22 * v2;

    if (valid) {
        float* __restrict__ o = out + (size_t)idx * 23;
        o[0]  = px; o[1]  = py; o[2]  = pz;
        o[3]  = s0; o[4]  = s1; o[5]  = s2;
        o[6]  = qw; o[7]  = qx; o[8]  = qy; o[9] = qz;
        o[10] = op;
        o[14] = c00; o[15] = c01; o[16] = c02;
        o[17] = c01; o[18] = c11; o[19] = c12;
        o[20] = c02; o[21] = c12; o[22] = c22;
    }
}

__global__ __launch_bounds__(BLOCK, 2)
void gsplat_fused_kernel(const float* __restrict__ positions,
                         const float* __restrict__ scales,
                         const float* __restrict__ rotations,
                         const float* __restrict__ opacity,
                         const float* __restrict__ features,
                         const float* __restrict__ w1, const float* __restrict__ b1,
                         const float* __restrict__ w2, const float* __restrict__ b2,
                         const float* __restrict__ w3, const float* __restrict__ b3,
                         float* __restrict__ out, int n)
{
    // LDS-staged weights: broadcast ds_read is ISA-guaranteed conflict-free.
    // w1 transposed -> [j][i] (layer-1 column j contiguous, 8x ds_read_b128).
    // w2 row-major ([j][k]). w3 transposed -> [m][k].
    __shared__ float sw1t[64 * 32];
    __shared__ float sw2[64 * 32];
    __shared__ float sw3t[3 * 32];
    __shared__ float sb1[64];
    __shared__ float sb2[32];
    __shared__ float sb3[3];

    for (int t = threadIdx.x; t < 2048; t += BLOCK) {
        int i = t >> 6, j = t & 63;
        sw1t[j * 32 + i] = w1[t];
    }
    for (int t = threadIdx.x; t < 2048; t += BLOCK) sw2[t] = w2[t];
    for (int t = threadIdx.x; t < 96; t += BLOCK) {
        int k = t / 3, m = t - 3 * k;
        sw3t[m * 32 + k] = w3[t];
    }
    if (threadIdx.x < 64) sb1[threadIdx.x] = b1[threadIdx.x];
    if (threadIdx.x < 32) sb2[threadIdx.x] = b2[threadIdx.x];
    if (threadIdx.x < 3)  sb3[threadIdx.x] = b3[threadIdx.x];
    __syncthreads();

    const int pA = blockIdx.x * (BLOCK * 2) + threadIdx.x;
    const int pB = pA + BLOCK;
    const bool vA = pA < n;
    const bool vB = pB < n;

    // Geometry first so its temporaries retire before the MLP's register peak.
    geom_one(pA, vA, n, positions, scales, rotations, opacity, out);
    geom_one(pB, vB, n, positions, scales, rotations, opacity, out);

    // ---------------- MLP: 32 -> 64 -> 32 -> 3, two points ----------------
    const size_t bA = (size_t)(vA ? pA : (n - 1));
    const size_t bB = (size_t)(vB ? pB : (n - 1));

    float fA[32], fB[32];
    {
        const float4* fpA = (const float4*)(features + bA * 32);
        const float4* fpB = (const float4*)(features + bB * 32);
        #pragma unroll
        for (int u = 0; u < 8; ++u) {
            const float4 a = fpA[u];
            fA[u * 4 + 0] = a.x; fA[u * 4 + 1] = a.y;
            fA[u * 4 + 2] = a.z; fA[u * 4 + 3] = a.w;
            const float4 b = fpB[u];
            fB[u * 4 + 0] = b.x; fB[u * 4 + 1] = b.y;
            fB[u * 4 + 2] = b.z; fB[u * 4 + 3] = b.w;
        }
    }

    float hA[32], hB[32];
    #pragma unroll
    for (int k = 0; k < 32; ++k) { float b = sb2[k]; hA[k] = b; hB[k] = b; }

    // Fused layer1+layer2. Each LDS weight fragment (16 broadcast ds_read_b128
    // per j) feeds 128 FMAs (2 points x (32+32)). All register arrays
    // statically indexed; j-loop rolled for small I-footprint.
    for (int j = 0; j < 64; ++j) {
        const float* __restrict__ wc = &sw1t[j * 32];
        const float bj = sb1[j];
        float a0 = bj,   a1 = 0.0f, a2 = 0.0f, a3 = 0.0f;
        float e0 = bj,   e1 = 0.0f, e2 = 0.0f, e3 = 0.0f;
        #pragma unroll
        for (int i = 0; i < 8; ++i) {
            const float w0 = wc[i * 4 + 0], w1v = wc[i * 4 + 1];
            const float w2v = wc[i * 4 + 2], w3v = wc[i * 4 + 3];
            a0 = fmaf(fA[i * 4 + 0], w0,  a0);
            a1 = fmaf(fA[i * 4 + 1], w1v, a1);
            a2 = fmaf(fA[i * 4 + 2], w2v, a2);
            a3 = fmaf(fA[i * 4 + 3], w3v, a3);
            e0 = fmaf(fB[i * 4 + 0], w0,  e0);
            e1 = fmaf(fB[i * 4 + 1], w1v, e1);
            e2 = fmaf(fB[i * 4 + 2], w2v, e2);
            e3 = fmaf(fB[i * 4 + 3], w3v, e3);
        }
        const float h1A = fmaxf((a0 + a1) + (a2 + a3), 0.0f);
        const float h1B = fmaxf((e0 + e1) + (e2 + e3), 0.0f);

        const float* __restrict__ w2r = &sw2[j * 32];
        #pragma unroll
        for (int k = 0; k < 32; ++k) {
            const float w = w2r[k];
            hA[k] = fmaf(h1A, w, hA[k]);
            hB[k] = fmaf(h1B, w, hB[k]);
        }
    }

    float cA0 = sb3[0], cA1 = sb3[1], cA2 = sb3[2];
    float cB0 = sb3[0], cB1 = sb3[1], cB2 = sb3[2];
    #pragma unroll
    for (int k = 0; k < 32; ++k) {
        const float w0 = sw3t[k], w1v = sw3t[32 + k], w2v = sw3t[64 + k];
        const float a = fmaxf(hA[k], 0.0f);
        const float b = fmaxf(hB[k], 0.0f);
        cA0 = fmaf(a, w0, cA0); cA1 = fmaf(a, w1v, cA1); cA2 = fmaf(a, w2v, cA2);
        cB0 = fmaf(b, w0, cB0); cB1 = fmaf(b, w1v, cB1); cB2 = fmaf(b, w2v, cB2);
    }

    if (vA) {
        float* __restrict__ o = out + (size_t)pA * 23;
        o[11] = 1.0f / (1.0f + __expf(-cA0));
        o[12] = 1.0f / (1.0f + __expf(-cA1));
        o[13] = 1.0f / (1.0f + __expf(-cA2));
    }
    if (vB) {
        float* __restrict__ o = out + (size_t)pB * 23;
        o[11] = 1.0f / (1.0f + __expf(-cB0));
        o[12] = 1.0f / (1.0f + __expf(-cB1));
        o[13] = 1.0f / (1.0f + __expf(-cB2));
    }
}

extern "C" void kernel_launch(void* const* d_in, const int* in_sizes, int n_in,
                              void* d_out, int out_size, void* d_ws, size_t ws_size,
                              hipStream_t stream) {
    const float* positions = (const float*)d_in[0];
    const float* scales    = (const float*)d_in[1];
    const float* rotations = (const float*)d_in[2];
    const float* opacity   = (const float*)d_in[3];
    const float* features  = (const float*)d_in[4];
    const float* w1        = (const float*)d_in[5];
    const float* b1        = (const float*)d_in[6];
    const float* w2        = (const float*)d_in[7];
    const float* b2        = (const float*)d_in[8];
    const float* w3        = (const float*)d_in[9];
    const float* b3        = (const float*)d_in[10];
    float* out = (float*)d_out;

    const int n = in_sizes[0] / 3;
    const int grid = (n + BLOCK * 2 - 1) / (BLOCK * 2);
    gsplat_fused_kernel<<<grid, BLOCK, 0, stream>>>(
        positions, scales, rotations, opacity, features,
        w1, b1, w2, b2, w3, b3, out, n);
}

// Round 4
// 549.843 us; speedup vs baseline: 1.1311x; 1.1311x over previous
//
#include <hip/hip_runtime.h>
#include <hip/hip_bf16.h>
#include <math.h>

#define BLOCK 256

typedef __attribute__((ext_vector_type(8))) short bf16x8;   // 8 bf16 = 4 VGPR
typedef __attribute__((ext_vector_type(4))) float f32x4;

static __device__ __forceinline__ short f2bf(float x) {
    __hip_bfloat16 h = __float2bfloat16(x);
    short s;
    __builtin_memcpy(&s, &h, 2);
    return s;
}

// -------- pre-pass: pack W1/W2/W3 into MFMA B-fragment order (bf16) --------
// ws layout (ushort units):
//   w1B [ht=4][lane=64][e=8]            @ 0      (B[k][n]: k=lkg*8+e, n=ht*16+lrow)
//   w2B [kt=2][jt=2][lane=64][e=8]      @ 2048   (k=kt*32+lkg*8+e, n=jt*16+lrow)
//   w3B [lane=64][e=8]                  @ 4096   (k=lkg*8+e, n=lrow<3 else 0)
__global__ void gsplat_pack_weights(const float* __restrict__ w1,
                                    const float* __restrict__ w2,
                                    const float* __restrict__ w3,
                                    ushort* __restrict__ ws)
{
    const int tid = threadIdx.x;
    for (int u = tid; u < 2048; u += BLOCK) {
        const int e = u & 7, lane = (u >> 3) & 63, ht = u >> 9;
        const int k = (lane >> 4) * 8 + e;
        const int j = ht * 16 + (lane & 15);
        ws[u] = (ushort)f2bf(w1[k * 64 + j]);
    }
    for (int u = tid; u < 2048; u += BLOCK) {
        const int e = u & 7, lane = (u >> 3) & 63, c = u >> 9;
        const int kt = c >> 1, jt = c & 1;
        const int k = kt * 32 + (lane >> 4) * 8 + e;
        const int j = jt * 16 + (lane & 15);
        ws[2048 + u] = (ushort)f2bf(w2[k * 32 + j]);
    }
    for (int u = tid; u < 512; u += BLOCK) {
        const int e = u & 7, lane = u >> 3;
        const int col = lane & 15;
        const int k = (lane >> 4) * 8 + e;
        ws[4096 + u] = (ushort)f2bf(col < 3 ? w3[k * 3 + col] : 0.0f);
    }
}

// -------- main fused kernel: geometry (f32 VALU) + MLP (bf16 MFMA) --------
__global__ __launch_bounds__(BLOCK, 4)
void gsplat_mfma_kernel(const float* __restrict__ positions,
                        const float* __restrict__ scales,
                        const float* __restrict__ rotations,
                        const float* __restrict__ opacity,
                        const float* __restrict__ features,
                        const ushort* __restrict__ wpack,
                        const float* __restrict__ b1,
                        const float* __restrict__ b2,
                        const float* __restrict__ b3,
                        float* __restrict__ out, int n)
{
    // Per-wave private LDS (no cross-wave sharing -> NO barriers anywhere).
    // H1: 16 rows x 72 ush (144 B pitch; 36 dwords = 4 mod 32 -> banks spread,
    // ds_read_b128 across rows is 2-way max = free). H2: 16 rows x 40 ush (80 B).
    __shared__ __align__(16) ushort lds[4 * 1792];

    const int tid  = threadIdx.x;
    const int wave = tid >> 6;
    const int lane = tid & 63;
    const int lrow = lane & 15;    // MFMA row/col within 16
    const int lkg  = lane >> 4;    // k-group (0..3)

    const int blockBase = blockIdx.x * BLOCK;

    // ---------------- geometry, one point per thread ----------------
    {
        const int pt = blockBase + tid;
        if (pt < n) {
            const size_t base = (size_t)pt;
            const float px = positions[base * 3 + 0];
            const float py = positions[base * 3 + 1];
            const float pz = positions[base * 3 + 2];

            const float s0 = __expf(scales[base * 3 + 0]);
            const float s1 = __expf(scales[base * 3 + 1]);
            const float s2 = __expf(scales[base * 3 + 2]);

            float qw = rotations[base * 4 + 0];
            float qx = rotations[base * 4 + 1];
            float qy = rotations[base * 4 + 2];
            float qz = rotations[base * 4 + 3];
            const float inv = rsqrtf(qw * qw + qx * qx + qy * qy + qz * qz);
            qw *= inv; qx *= inv; qy *= inv; qz *= inv;

            float op = opacity[base];
            op = 1.0f / (1.0f + __expf(-op));

            const float r00 = 1.0f - 2.0f * (qy * qy + qz * qz);
            const float r01 = 2.0f * (qx * qy - qw * qz);
            const float r02 = 2.0f * (qx * qz + qw * qy);
            const float r10 = 2.0f * (qx * qy + qw * qz);
            const float r11 = 1.0f - 2.0f * (qx * qx + qz * qz);
            const float r12 = 2.0f * (qy * qz - qw * qx);
            const float r20 = 2.0f * (qx * qz - qw * qy);
            const float r21 = 2.0f * (qy * qz + qw * qx);
            const float r22 = 1.0f - 2.0f * (qx * qx + qy * qy);

            const float v0 = s0 * s0, v1 = s1 * s1, v2 = s2 * s2;
            const float c00 = r00 * r00 * v0 + r01 * r01 * v1 + r02 * r02 * v2;
            const float c01 = r00 * r10 * v0 + r01 * r11 * v1 + r02 * r12 * v2;
            const float c02 = r00 * r20 * v0 + r01 * r21 * v1 + r02 * r22 * v2;
            const float c11 = r10 * r10 * v0 + r11 * r11 * v1 + r12 * r12 * v2;
            const float c12 = r10 * r20 * v0 + r11 * r21 * v1 + r12 * r22 * v2;
            const float c22 = r20 * r20 * v0 + r21 * r21 * v1 + r22 * r22 * v2;

            float* __restrict__ o = out + base * 23;
            o[0]  = px; o[1]  = py; o[2]  = pz;
            o[3]  = s0; o[4]  = s1; o[5]  = s2;
            o[6]  = qw; o[7]  = qx; o[8]  = qy; o[9] = qz;
            o[10] = op;
            o[14] = c00; o[15] = c01; o[16] = c02;
            o[17] = c01; o[18] = c11; o[19] = c12;
            o[20] = c02; o[21] = c12; o[22] = c22;
        }
    }

    // ---------------- weights: 9 coalesced 16B loads, L2-resident ----------------
    const bf16x8* wp = (const bf16x8*)wpack;
    bf16x8 w1f[4];
    #pragma unroll
    for (int ht = 0; ht < 4; ++ht) w1f[ht] = wp[ht * 64 + lane];
    bf16x8 w2f[2][2];
    #pragma unroll
    for (int kt = 0; kt < 2; ++kt)
        #pragma unroll
        for (int jt = 0; jt < 2; ++jt)
            w2f[kt][jt] = wp[256 + (kt * 2 + jt) * 64 + lane];
    const bf16x8 w3f = wp[512 + lane];

    float b1v[4];
    #pragma unroll
    for (int ht = 0; ht < 4; ++ht) b1v[ht] = b1[ht * 16 + lrow];
    float b2v[2];
    #pragma unroll
    for (int jt = 0; jt < 2; ++jt) b2v[jt] = b2[jt * 16 + lrow];
    const float b3v = (lrow < 3) ? b3[lrow] : 0.0f;

    ushort* h1 = &lds[wave * 1792];   // pitch 72 ushorts
    ushort* h2 = h1 + 1152;           // pitch 40 ushorts

    const int waveBase = blockBase + wave * 64;
    const f32x4 zero = {0.0f, 0.0f, 0.0f, 0.0f};

    for (int p = 0; p < 4; ++p) {
        const int pt0 = waveBase + p * 16;

        // A1 fragment: row = pt0+lrow, k = lkg*8..+7 (8 consecutive f32 -> bf16)
        int ptA = pt0 + lrow;
        if (ptA >= n) ptA = n - 1;
        const float* fsrc = features + (size_t)ptA * 32 + lkg * 8;
        const float4 fa = *(const float4*)(fsrc);
        const float4 fb = *(const float4*)(fsrc + 4);
        bf16x8 a1;
        a1[0] = f2bf(fa.x); a1[1] = f2bf(fa.y); a1[2] = f2bf(fa.z); a1[3] = f2bf(fa.w);
        a1[4] = f2bf(fb.x); a1[5] = f2bf(fb.y); a1[6] = f2bf(fb.z); a1[7] = f2bf(fb.w);

        // ---- layer 1: h1(16x64) = A1(16x32) @ W1(32x64) ----
        f32x4 c1[4];
        #pragma unroll
        for (int ht = 0; ht < 4; ++ht)
            c1[ht] = __builtin_amdgcn_mfma_f32_16x16x32_bf16(a1, w1f[ht], zero, 0, 0, 0);

        // bias + relu + bf16 -> LDS (row = point = lkg*4+r, col = ht*16+lrow)
        const int h1w = (lkg * 4) * 72 + lrow;
        #pragma unroll
        for (int ht = 0; ht < 4; ++ht)
            #pragma unroll
            for (int r = 0; r < 4; ++r)
                h1[h1w + r * 72 + ht * 16] =
                    (ushort)f2bf(fmaxf(c1[ht][r] + b1v[ht], 0.0f));

        // ---- layer 2: h2(16x32) = relu(h1)(16x64) @ W2(64x32), K as 2x32 ----
        const bf16x8* h1r = (const bf16x8*)(h1 + lrow * 72);  // my point-row
        const bf16x8 a2lo = h1r[lkg];       // k = lkg*8      (0..31)
        const bf16x8 a2hi = h1r[4 + lkg];   // k = 32+lkg*8   (32..63)

        f32x4 c2[2];
        #pragma unroll
        for (int jt = 0; jt < 2; ++jt) {
            f32x4 acc = __builtin_amdgcn_mfma_f32_16x16x32_bf16(a2lo, w2f[0][jt], zero, 0, 0, 0);
            c2[jt]    = __builtin_amdgcn_mfma_f32_16x16x32_bf16(a2hi, w2f[1][jt], acc, 0, 0, 0);
        }

        const int h2w = (lkg * 4) * 40 + lrow;
        #pragma unroll
        for (int jt = 0; jt < 2; ++jt)
            #pragma unroll
            for (int r = 0; r < 4; ++r)
                h2[h2w + r * 40 + jt * 16] =
                    (ushort)f2bf(fmaxf(c2[jt][r] + b2v[jt], 0.0f));

        // ---- layer 3: colors(16x3) = h2(16x32) @ W3(32x16, cols>=3 zero) ----
        const bf16x8* h2r = (const bf16x8*)(h2 + lrow * 40);
        const bf16x8 a3 = h2r[lkg];
        const f32x4 c3 = __builtin_amdgcn_mfma_f32_16x16x32_bf16(a3, w3f, zero, 0, 0, 0);

        if (lrow < 3) {
            #pragma unroll
            for (int r = 0; r < 4; ++r) {
                const int pt = pt0 + lkg * 4 + r;
                if (pt < n)
                    out[(size_t)pt * 23 + 11 + lrow] =
                        1.0f / (1.0f + __expf(-(c3[r] + b3v)));
            }
        }
    }
}

extern "C" void kernel_launch(void* const* d_in, const int* in_sizes, int n_in,
                              void* d_out, int out_size, void* d_ws, size_t ws_size,
                              hipStream_t stream) {
    const float* positions = (const float*)d_in[0];
    const float* scales    = (const float*)d_in[1];
    const float* rotations = (const float*)d_in[2];
    const float* opacity   = (const float*)d_in[3];
    const float* features  = (const float*)d_in[4];
    const float* w1        = (const float*)d_in[5];
    const float* b1        = (const float*)d_in[6];
    const float* w2        = (const float*)d_in[7];
    const float* b2        = (const float*)d_in[8];
    const float* w3        = (const float*)d_in[9];
    const float* b3        = (const float*)d_in[10];
    float* out = (float*)d_out;

    ushort* wpack = (ushort*)d_ws;   // 4608 ushorts = 9216 B

    gsplat_pack_weights<<<1, BLOCK, 0, stream>>>(w1, w2, w3, wpack);

    const int n = in_sizes[0] / 3;
    const int grid = (n + BLOCK - 1) / BLOCK;
    gsplat_mfma_kernel<<<grid, BLOCK, 0, stream>>>(
        positions, scales, rotations, opacity, features,
        wpack, b1, b2, b3, out, n);
}